// Round 1
// baseline (2377.345 us; speedup 1.0000x reference)
//
#include <hip/hip_runtime.h>
#include <hip/hip_bf16.h>

#define NN 100000      // nodes
#define NR 4           // relations
#define NE 400000      // edges per relation
#define INF 128
#define HF 128
#define OUTF 64

// ---------------- degree histogram (float, exact for small counts) -------
__global__ void deg_kernel(const int* __restrict__ src, const int* __restrict__ dst,
                           float* __restrict__ deg_out, float* __restrict__ deg_in) {
    int r = blockIdx.y;
    int i = blockIdx.x * blockDim.x + threadIdx.x;
    if (i >= NE) return;
    int s = src[(size_t)r * NE + i];
    int d = dst[(size_t)r * NE + i];
    unsafeAtomicAdd(&deg_out[(size_t)r * NN + s], 1.0f);
    unsafeAtomicAdd(&deg_in [(size_t)r * NN + d], 1.0f);
}

// deg -> rsqrt(max(deg,1)) in place (covers both arrays contiguously)
__global__ void rsqrt_kernel(float* __restrict__ buf, int n) {
    int i = blockIdx.x * blockDim.x + threadIdx.x;
    if (i < n) buf[i] = rsqrtf(fmaxf(buf[i], 1.0f));
}

// per-edge coefficient = rn_out[src] * rn_in[dst]  (same for both layers)
__global__ void coeff_kernel(const int* __restrict__ src, const int* __restrict__ dst,
                             const float* __restrict__ rno, const float* __restrict__ rni,
                             float* __restrict__ coeff) {
    int r = blockIdx.y;
    int i = blockIdx.x * blockDim.x + threadIdx.x;
    if (i >= NE) return;
    int s = src[(size_t)r * NE + i];
    int d = dst[(size_t)r * NE + i];
    coeff[(size_t)r * NE + i] = rno[(size_t)r * NN + s] * rni[(size_t)r * NN + d];
}

// sum biases across relations: bsum1[128], bsum2[64]
__global__ void bsum_kernel(const float* __restrict__ b1, const float* __restrict__ b2,
                            float* __restrict__ bsum1, float* __restrict__ bsum2) {
    int t = threadIdx.x;
    if (t < HF) {
        float s = 0.f;
        for (int r = 0; r < NR; r++) s += b1[r * HF + t];
        bsum1[t] = s;
    } else if (t < HF + OUTF) {
        int f = t - HF;
        float s = 0.f;
        for (int r = 0; r < NR; r++) s += b2[r * OUTF + f];
        bsum2[f] = s;
    }
}

// out[n][f] = bsum[f]  (accumulator init; fmask = row stride - 1, power of 2)
__global__ void init_bias_kernel(float* __restrict__ out, const float* __restrict__ bsum,
                                 int fmask, int total4) {
    int i = blockIdx.x * blockDim.x + threadIdx.x;
    if (i >= total4) return;
    int f = (i * 4) & fmask;
    float4 b = *(const float4*)(bsum + f);
    ((float4*)out)[i] = b;
}

__global__ void relu_kernel(float* __restrict__ h, int total4) {
    int i = blockIdx.x * blockDim.x + threadIdx.x;
    if (i >= total4) return;
    float4 v = ((float4*)h)[i];
    v.x = fmaxf(v.x, 0.f); v.y = fmaxf(v.y, 0.f);
    v.z = fmaxf(v.z, 0.f); v.w = fmaxf(v.w, 0.f);
    ((float4*)h)[i] = v;
}

__device__ __forceinline__ void fma4(float4& a, float s, const float4& w) {
    a.x = fmaf(s, w.x, a.x); a.y = fmaf(s, w.y, a.y);
    a.z = fmaf(s, w.z, a.z); a.w = fmaf(s, w.w, a.w);
}

// ---------------- fp32 GEMM:  Z[N, F] = X[N, 128] @ W[128, F] ------------
// block = 256 threads; thread computes 4 nodes x 4 feats.
template<int F>
__global__ void gemm_kernel(const float* __restrict__ X, const float* __restrict__ W,
                            float* __restrict__ Z) {
    constexpr int K = 128;
    constexpr int LDA = K + 4;            // pad to dodge bank conflicts
    constexpr int TPR = F / 4;            // threads covering the feature dim
    constexpr int NG  = 256 / TPR;        // node groups per block
    constexpr int TILE_N = NG * 4;        // 32 (F=128) or 64 (F=64)
    __shared__ float xs[TILE_N][LDA];

    int t  = threadIdx.x;
    int f4 = t % TPR;                     // feature quad
    int ng = t / TPR;                     // node group (4 nodes)
    int n0 = blockIdx.x * TILE_N;

    // stage X tile (clamp OOB rows; their results are never stored)
    constexpr int LD4 = TILE_N * K / 4;
    for (int idx = t; idx < LD4; idx += 256) {
        int row = idx / (K / 4);
        int c4  = idx % (K / 4);
        int n = n0 + row; if (n >= NN) n = NN - 1;
        *(float4*)&xs[row][c4 * 4] = *(const float4*)(X + (size_t)n * K + c4 * 4);
    }
    __syncthreads();

    float4 acc[4];
    acc[0] = acc[1] = acc[2] = acc[3] = make_float4(0.f, 0.f, 0.f, 0.f);
    const float* xrow = &xs[ng * 4][0];
    const float* Wp = W + f4 * 4;

    #pragma unroll 4
    for (int k = 0; k < K; k++) {
        float4 w = *(const float4*)(Wp + (size_t)k * F);
        fma4(acc[0], xrow[k],            w);
        fma4(acc[1], xrow[LDA + k],      w);
        fma4(acc[2], xrow[2 * LDA + k],  w);
        fma4(acc[3], xrow[3 * LDA + k],  w);
    }

    #pragma unroll
    for (int j = 0; j < 4; j++) {
        int n = n0 + ng * 4 + j;
        if (n < NN) *(float4*)(Z + (size_t)n * F + f4 * 4) = acc[j];
    }
}

// ---------------- edge scatter: acc[dst] += coeff * Z[src] ---------------
// one wave (64 lanes) per edge; F=128 -> 2 floats/lane, F=64 -> 1 float/lane
template<int F>
__global__ void edge_scatter_kernel(const int* __restrict__ src, const int* __restrict__ dst,
                                    const float* __restrict__ coeff,
                                    const float* __restrict__ Z, float* __restrict__ acc) {
    int lane = threadIdx.x & 63;
    int e = blockIdx.x * 4 + (threadIdx.x >> 6);
    if (e >= NE) return;
    int s = src[e];
    int d = dst[e];
    float c = coeff[e];
    if constexpr (F == 128) {
        float2 v = *(const float2*)(Z + (size_t)s * F + lane * 2);
        unsafeAtomicAdd(acc + (size_t)d * F + lane * 2,     c * v.x);
        unsafeAtomicAdd(acc + (size_t)d * F + lane * 2 + 1, c * v.y);
    } else {
        float v = Z[(size_t)s * F + lane];
        unsafeAtomicAdd(acc + (size_t)d * F + lane, c * v);
    }
}

extern "C" void kernel_launch(void* const* d_in, const int* in_sizes, int n_in,
                              void* d_out, int out_size, void* d_ws, size_t ws_size,
                              hipStream_t stream) {
    const float* x   = (const float*)d_in[0];
    const int*   src = (const int*)  d_in[1];   // [4, 400000]
    const int*   dst = (const int*)  d_in[2];
    const float* W1  = (const float*)d_in[3];   // [4,128,128]
    const float* b1  = (const float*)d_in[4];   // [4,128]
    const float* W2  = (const float*)d_in[5];   // [4,128,64]
    const float* b2  = (const float*)d_in[6];   // [4,64]
    float* out = (float*)d_out;                 // [100000,64]

    char* p = (char*)d_ws;
    float* rn_out = (float*)p; p += (size_t)NR * NN * 4;   // 1.6 MB
    float* rn_in  = (float*)p; p += (size_t)NR * NN * 4;   // 1.6 MB (contiguous w/ rn_out)
    float* coeff  = (float*)p; p += (size_t)NR * NE * 4;   // 6.4 MB
    float* bsum1  = (float*)p; p += HF * 4;
    float* bsum2  = (float*)p; p += OUTF * 4;
    float* h      = (float*)p; p += (size_t)NN * HF * 4;   // 51.2 MB
    float* Z      = (float*)p; p += (size_t)NN * INF * 4;  // 51.2 MB (reused per rel/layer)

    // degrees -> rsqrt norms -> per-edge coeffs
    hipMemsetAsync(rn_out, 0, (size_t)2 * NR * NN * 4, stream);
    deg_kernel<<<dim3((NE + 255) / 256, NR), 256, 0, stream>>>(src, dst, rn_out, rn_in);
    rsqrt_kernel<<<(2 * NR * NN + 255) / 256, 256, 0, stream>>>(rn_out, 2 * NR * NN);
    coeff_kernel<<<dim3((NE + 255) / 256, NR), 256, 0, stream>>>(src, dst, rn_out, rn_in, coeff);
    bsum_kernel<<<1, 192, 0, stream>>>(b1, b2, bsum1, bsum2);

    // layer 1: h = relu( sum_r scatter(coeff_r, x @ W1_r) + bsum1 )
    init_bias_kernel<<<(NN * HF / 4 + 255) / 256, 256, 0, stream>>>(h, bsum1, HF - 1, NN * HF / 4);
    for (int r = 0; r < NR; r++) {
        gemm_kernel<HF><<<(NN + 31) / 32, 256, 0, stream>>>(x, W1 + (size_t)r * INF * HF, Z);
        edge_scatter_kernel<HF><<<(NE + 3) / 4, 256, 0, stream>>>(
            src + (size_t)r * NE, dst + (size_t)r * NE, coeff + (size_t)r * NE, Z, h);
    }
    relu_kernel<<<(NN * HF / 4 + 255) / 256, 256, 0, stream>>>(h, NN * HF / 4);

    // layer 2: out = sum_r scatter(coeff_r, h @ W2_r) + bsum2
    init_bias_kernel<<<(NN * OUTF / 4 + 255) / 256, 256, 0, stream>>>(out, bsum2, OUTF - 1, NN * OUTF / 4);
    for (int r = 0; r < NR; r++) {
        gemm_kernel<OUTF><<<(NN + 63) / 64, 256, 0, stream>>>(h, W2 + (size_t)r * HF * OUTF, Z);
        edge_scatter_kernel<OUTF><<<(NE + 3) / 4, 256, 0, stream>>>(
            src + (size_t)r * NE, dst + (size_t)r * NE, coeff + (size_t)r * NE, Z, out);
    }
}

// Round 2
// 1156.537 us; speedup vs baseline: 2.0556x; 2.0556x over previous
//
#include <hip/hip_runtime.h>
#include <hip/hip_bf16.h>

#define NN 100000      // nodes
#define NR 4           // relations
#define NE 400000      // edges per relation
#define INF 128
#define HF 128
#define OUTF 64

// ---------------- int degree histogram ----------------------------------
__global__ void deg_kernel(const int* __restrict__ src, const int* __restrict__ dst,
                           int* __restrict__ deg_out, int* __restrict__ deg_in) {
    int r = blockIdx.y;
    int i = blockIdx.x * blockDim.x + threadIdx.x;
    if (i >= NE) return;
    int s = src[(size_t)r * NE + i];
    int d = dst[(size_t)r * NE + i];
    atomicAdd(&deg_out[(size_t)r * NN + s], 1);
    atomicAdd(&deg_in [(size_t)r * NN + d], 1);
}

// rno[i] = rsqrt(max(deg_out[i],1)); rni[i] = rsqrt(max(deg_in[i],1))
__global__ void norm_kernel(const int* __restrict__ dego, const int* __restrict__ degi,
                            float* __restrict__ rno, float* __restrict__ rni, int n) {
    int i = blockIdx.x * blockDim.x + threadIdx.x;
    if (i >= n) return;
    rno[i] = rsqrtf(fmaxf((float)dego[i], 1.0f));
    rni[i] = rsqrtf(fmaxf((float)degi[i], 1.0f));
}

// ---------------- exclusive scan over deg_in (NR*NN entries) -------------
// pass 1: per-block (1024 elems, 256 thr) exclusive scan + block sums
__global__ void scan_block_kernel(const int* __restrict__ in, int* __restrict__ out,
                                  int* __restrict__ blockSums, int n) {
    __shared__ int sd[256];
    int t = threadIdx.x;
    int base = blockIdx.x * 1024 + t * 4;
    int v[4];
    #pragma unroll
    for (int j = 0; j < 4; j++) v[j] = (base + j < n) ? in[base + j] : 0;
    int ts = v[0] + v[1] + v[2] + v[3];
    sd[t] = ts;
    __syncthreads();
    int acc = ts;
    for (int off = 1; off < 256; off <<= 1) {
        int x = (t >= off) ? sd[t - off] : 0;
        __syncthreads();
        acc += x; sd[t] = acc;
        __syncthreads();
    }
    int run = acc - ts;   // exclusive prefix of this thread's quad
    #pragma unroll
    for (int j = 0; j < 4; j++) {
        if (base + j < n) out[base + j] = run;
        run += v[j];
    }
    if (t == 255) blockSums[blockIdx.x] = acc;
}

// pass 2: single block scans the block sums (nb <= 512) -> exclusive
__global__ void scan_sums_kernel(int* __restrict__ blockSums, int nb) {
    __shared__ int sd[512];
    int t = threadIdx.x;
    int v = (t < nb) ? blockSums[t] : 0;
    sd[t] = v;
    __syncthreads();
    int acc = v;
    for (int off = 1; off < 512; off <<= 1) {
        int x = (t >= off) ? sd[t - off] : 0;
        __syncthreads();
        acc += x; sd[t] = acc;
        __syncthreads();
    }
    if (t < nb) blockSums[t] = acc - v;   // exclusive
}

// pass 3: add block offsets; also mirror into cursor; row_ptr[n] = total
__global__ void scan_add_kernel(int* __restrict__ row_ptr, const int* __restrict__ blockSums,
                                int* __restrict__ cursor, int n) {
    int i = blockIdx.x * blockDim.x + threadIdx.x;
    if (i < n) {
        int v = row_ptr[i] + blockSums[i >> 10];
        row_ptr[i] = v;
        cursor[i] = v;
    }
    if (i == 0) row_ptr[n] = NR * NE;
}

// ---------------- CSR build: scatter (src, coeff) into dst-sorted order --
__global__ void csr_build_kernel(const int* __restrict__ src, const int* __restrict__ dst,
                                 const float* __restrict__ rno, const float* __restrict__ rni,
                                 int* __restrict__ cursor, int* __restrict__ src_sorted,
                                 float* __restrict__ coeff_sorted) {
    int r = blockIdx.y;
    int i = blockIdx.x * blockDim.x + threadIdx.x;
    if (i >= NE) return;
    int s = src[(size_t)r * NE + i];
    int d = dst[(size_t)r * NE + i];
    int pos = atomicAdd(&cursor[(size_t)r * NN + d], 1);
    src_sorted[pos] = s;
    coeff_sorted[pos] = rno[(size_t)r * NN + s] * rni[(size_t)r * NN + d];
}

// sum biases across relations: bsum1[128], bsum2[64]
__global__ void bsum_kernel(const float* __restrict__ b1, const float* __restrict__ b2,
                            float* __restrict__ bsum1, float* __restrict__ bsum2) {
    int t = threadIdx.x;
    if (t < HF) {
        float s = 0.f;
        for (int r = 0; r < NR; r++) s += b1[r * HF + t];
        bsum1[t] = s;
    } else if (t < HF + OUTF) {
        int f = t - HF;
        float s = 0.f;
        for (int r = 0; r < NR; r++) s += b2[r * OUTF + f];
        bsum2[f] = s;
    }
}

__device__ __forceinline__ void fma4(float4& a, float s, const float4& w) {
    a.x = fmaf(s, w.x, a.x); a.y = fmaf(s, w.y, a.y);
    a.z = fmaf(s, w.z, a.z); a.w = fmaf(s, w.w, a.w);
}

// ---------------- fp32 GEMM:  Z[N, F] = X[N, 128] @ W[128, F] ------------
template<int F>
__global__ void gemm_kernel(const float* __restrict__ X, const float* __restrict__ W,
                            float* __restrict__ Z) {
    constexpr int K = 128;
    constexpr int LDA = K + 4;
    constexpr int TPR = F / 4;
    constexpr int NG  = 256 / TPR;
    constexpr int TILE_N = NG * 4;
    __shared__ float xs[TILE_N][LDA];

    int t  = threadIdx.x;
    int f4 = t % TPR;
    int ng = t / TPR;
    int n0 = blockIdx.x * TILE_N;

    constexpr int LD4 = TILE_N * K / 4;
    for (int idx = t; idx < LD4; idx += 256) {
        int row = idx / (K / 4);
        int c4  = idx % (K / 4);
        int n = n0 + row; if (n >= NN) n = NN - 1;
        *(float4*)&xs[row][c4 * 4] = *(const float4*)(X + (size_t)n * K + c4 * 4);
    }
    __syncthreads();

    float4 acc[4];
    acc[0] = acc[1] = acc[2] = acc[3] = make_float4(0.f, 0.f, 0.f, 0.f);
    const float* xrow = &xs[ng * 4][0];
    const float* Wp = W + f4 * 4;

    #pragma unroll 4
    for (int k = 0; k < K; k++) {
        float4 w = *(const float4*)(Wp + (size_t)k * F);
        fma4(acc[0], xrow[k],            w);
        fma4(acc[1], xrow[LDA + k],      w);
        fma4(acc[2], xrow[2 * LDA + k],  w);
        fma4(acc[3], xrow[3 * LDA + k],  w);
    }

    #pragma unroll
    for (int j = 0; j < 4; j++) {
        int n = n0 + ng * 4 + j;
        if (n < NN) *(float4*)(Z + (size_t)n * F + f4 * 4) = acc[j];
    }
}

// ---------------- CSR gather: acc[n] (+)= sum_e coeff_e * Z[src_e] -------
// one wave per dst node; FIRST: init from bsum; RELU: clamp before store
template<int F, bool FIRST, bool RELU>
__global__ void gather_kernel(const int* __restrict__ row_ptr, const int* __restrict__ src_sorted,
                              const float* __restrict__ coeff_sorted,
                              const float* __restrict__ Z, float* __restrict__ acc,
                              const float* __restrict__ bsum, int relbase) {
    int wid  = threadIdx.x >> 6;
    int lane = threadIdx.x & 63;
    int n = blockIdx.x * (blockDim.x >> 6) + wid;
    if (n >= NN) return;
    int beg = row_ptr[relbase + n];
    int end = row_ptr[relbase + n + 1];

    if constexpr (F == 128) {
        float2 a;
        if constexpr (FIRST) a = *(const float2*)(bsum + lane * 2);
        else                 a = *(const float2*)(acc + (size_t)n * F + lane * 2);
        for (int p = beg; p < end; p++) {
            int s = src_sorted[p];
            float c = coeff_sorted[p];
            float2 v = *(const float2*)(Z + (size_t)s * F + lane * 2);
            a.x = fmaf(c, v.x, a.x);
            a.y = fmaf(c, v.y, a.y);
        }
        if constexpr (RELU) { a.x = fmaxf(a.x, 0.f); a.y = fmaxf(a.y, 0.f); }
        *(float2*)(acc + (size_t)n * F + lane * 2) = a;
    } else {
        float a;
        if constexpr (FIRST) a = bsum[lane];
        else                 a = acc[(size_t)n * F + lane];
        for (int p = beg; p < end; p++) {
            int s = src_sorted[p];
            float c = coeff_sorted[p];
            a = fmaf(c, Z[(size_t)s * F + lane], a);
        }
        if constexpr (RELU) a = fmaxf(a, 0.f);
        acc[(size_t)n * F + lane] = a;
    }
}

extern "C" void kernel_launch(void* const* d_in, const int* in_sizes, int n_in,
                              void* d_out, int out_size, void* d_ws, size_t ws_size,
                              hipStream_t stream) {
    const float* x   = (const float*)d_in[0];
    const int*   src = (const int*)  d_in[1];   // [4, 400000]
    const int*   dst = (const int*)  d_in[2];
    const float* W1  = (const float*)d_in[3];   // [4,128,128]
    const float* b1  = (const float*)d_in[4];   // [4,128]
    const float* W2  = (const float*)d_in[5];   // [4,128,64]
    const float* b2  = (const float*)d_in[6];   // [4,64]
    float* out = (float*)d_out;                 // [100000,64]

    constexpr int RN = NR * NN;                 // 400000 rows total
    constexpr int NB = (RN + 1023) / 1024;      // scan blocks (391)

    char* p = (char*)d_ws;
    int*   deg_out_i = (int*)p;   p += (size_t)RN * 4;       // 1.6 MB
    int*   deg_in_i  = (int*)p;   p += (size_t)RN * 4;
    float* rno       = (float*)p; p += (size_t)RN * 4;
    float* rni       = (float*)p; p += (size_t)RN * 4;
    int*   row_ptr   = (int*)p;   p += ((size_t)RN + 16) * 4;
    int*   cursor    = (int*)p;   p += (size_t)RN * 4;
    int*   blockSums = (int*)p;   p += 1024 * 4;
    int*   src_sorted   = (int*)p;   p += (size_t)NR * NE * 4;  // 6.4 MB
    float* coeff_sorted = (float*)p; p += (size_t)NR * NE * 4;  // 6.4 MB
    float* bsum1 = (float*)p; p += HF * 4;
    float* bsum2 = (float*)p; p += OUTF * 4;
    float* h     = (float*)p; p += (size_t)NN * HF * 4;      // 51.2 MB
    float* Z     = (float*)p; p += (size_t)NN * HF * 4;      // 51.2 MB

    // ---- CSR build (once; reused by both layers) ----
    hipMemsetAsync(deg_out_i, 0, (size_t)2 * RN * 4, stream);  // deg_out + deg_in
    deg_kernel<<<dim3((NE + 255) / 256, NR), 256, 0, stream>>>(src, dst, deg_out_i, deg_in_i);
    norm_kernel<<<(RN + 255) / 256, 256, 0, stream>>>(deg_out_i, deg_in_i, rno, rni, RN);
    scan_block_kernel<<<NB, 256, 0, stream>>>(deg_in_i, row_ptr, blockSums, RN);
    scan_sums_kernel<<<1, 512, 0, stream>>>(blockSums, NB);
    scan_add_kernel<<<(RN + 255) / 256, 256, 0, stream>>>(row_ptr, blockSums, cursor, RN);
    csr_build_kernel<<<dim3((NE + 255) / 256, NR), 256, 0, stream>>>(
        src, dst, rno, rni, cursor, src_sorted, coeff_sorted);
    bsum_kernel<<<1, 192, 0, stream>>>(b1, b2, bsum1, bsum2);

    // ---- layer 1: h = relu( sum_r gather_r(x @ W1_r) + bsum1 ) ----
    for (int r = 0; r < NR; r++) {
        gemm_kernel<HF><<<(NN + 31) / 32, 256, 0, stream>>>(x, W1 + (size_t)r * INF * HF, Z);
        if (r == 0)
            gather_kernel<HF, true, false><<<(NN + 3) / 4, 256, 0, stream>>>(
                row_ptr, src_sorted, coeff_sorted, Z, h, bsum1, r * NN);
        else if (r == NR - 1)
            gather_kernel<HF, false, true><<<(NN + 3) / 4, 256, 0, stream>>>(
                row_ptr, src_sorted, coeff_sorted, Z, h, bsum1, r * NN);
        else
            gather_kernel<HF, false, false><<<(NN + 3) / 4, 256, 0, stream>>>(
                row_ptr, src_sorted, coeff_sorted, Z, h, bsum1, r * NN);
    }

    // ---- layer 2: out = sum_r gather_r(h @ W2_r) + bsum2 ----
    for (int r = 0; r < NR; r++) {
        gemm_kernel<OUTF><<<(NN + 63) / 64, 256, 0, stream>>>(h, W2 + (size_t)r * HF * OUTF, Z);
        if (r == 0)
            gather_kernel<OUTF, true, false><<<(NN + 3) / 4, 256, 0, stream>>>(
                row_ptr, src_sorted, coeff_sorted, Z, out, bsum2, r * NN);
        else
            gather_kernel<OUTF, false, false><<<(NN + 3) / 4, 256, 0, stream>>>(
                row_ptr, src_sorted, coeff_sorted, Z, out, bsum2, r * NN);
    }
}

// Round 3
// 857.570 us; speedup vs baseline: 2.7722x; 1.3486x over previous
//
#include <hip/hip_runtime.h>
#include <hip/hip_bf16.h>

#define NN 100000      // nodes
#define NR 4           // relations
#define NE 400000      // edges per relation
#define INF 128
#define HF 128
#define OUTF 64

typedef __attribute__((ext_vector_type(8))) short s16x8;   // 8 bf16 (4 VGPRs)
typedef __attribute__((ext_vector_type(4))) float f32x4;   // MFMA C/D

// ---------------- int degree histogram ----------------------------------
__global__ void deg_kernel(const int* __restrict__ src, const int* __restrict__ dst,
                           int* __restrict__ deg_out, int* __restrict__ deg_in) {
    int r = blockIdx.y;
    int i = blockIdx.x * blockDim.x + threadIdx.x;
    if (i >= NE) return;
    int s = src[(size_t)r * NE + i];
    int d = dst[(size_t)r * NE + i];
    atomicAdd(&deg_out[(size_t)r * NN + s], 1);
    atomicAdd(&deg_in [(size_t)r * NN + d], 1);
}

__global__ void norm_kernel(const int* __restrict__ dego, const int* __restrict__ degi,
                            float* __restrict__ rno, float* __restrict__ rni, int n) {
    int i = blockIdx.x * blockDim.x + threadIdx.x;
    if (i >= n) return;
    rno[i] = rsqrtf(fmaxf((float)dego[i], 1.0f));
    rni[i] = rsqrtf(fmaxf((float)degi[i], 1.0f));
}

// ---------------- exclusive scan over deg_in (NR*NN entries) -------------
__global__ void scan_block_kernel(const int* __restrict__ in, int* __restrict__ out,
                                  int* __restrict__ blockSums, int n) {
    __shared__ int sd[256];
    int t = threadIdx.x;
    int base = blockIdx.x * 1024 + t * 4;
    int v[4];
    #pragma unroll
    for (int j = 0; j < 4; j++) v[j] = (base + j < n) ? in[base + j] : 0;
    int ts = v[0] + v[1] + v[2] + v[3];
    sd[t] = ts;
    __syncthreads();
    int acc = ts;
    for (int off = 1; off < 256; off <<= 1) {
        int x = (t >= off) ? sd[t - off] : 0;
        __syncthreads();
        acc += x; sd[t] = acc;
        __syncthreads();
    }
    int run = acc - ts;
    #pragma unroll
    for (int j = 0; j < 4; j++) {
        if (base + j < n) out[base + j] = run;
        run += v[j];
    }
    if (t == 255) blockSums[blockIdx.x] = acc;
}

__global__ void scan_sums_kernel(int* __restrict__ blockSums, int nb) {
    __shared__ int sd[512];
    int t = threadIdx.x;
    int v = (t < nb) ? blockSums[t] : 0;
    sd[t] = v;
    __syncthreads();
    int acc = v;
    for (int off = 1; off < 512; off <<= 1) {
        int x = (t >= off) ? sd[t - off] : 0;
        __syncthreads();
        acc += x; sd[t] = acc;
        __syncthreads();
    }
    if (t < nb) blockSums[t] = acc - v;
}

__global__ void scan_add_kernel(int* __restrict__ row_ptr, const int* __restrict__ blockSums,
                                int* __restrict__ cursor, int n) {
    int i = blockIdx.x * blockDim.x + threadIdx.x;
    if (i < n) {
        int v = row_ptr[i] + blockSums[i >> 10];
        row_ptr[i] = v;
        cursor[i] = v;
    }
    if (i == 0) row_ptr[n] = NR * NE;
}

// ---------------- CSR build: scatter (src, coeff) into dst-sorted order --
__global__ void csr_build_kernel(const int* __restrict__ src, const int* __restrict__ dst,
                                 const float* __restrict__ rno, const float* __restrict__ rni,
                                 int* __restrict__ cursor, int* __restrict__ src_sorted,
                                 float* __restrict__ coeff_sorted) {
    int r = blockIdx.y;
    int i = blockIdx.x * blockDim.x + threadIdx.x;
    if (i >= NE) return;
    int s = src[(size_t)r * NE + i];
    int d = dst[(size_t)r * NE + i];
    int pos = atomicAdd(&cursor[(size_t)r * NN + d], 1);
    src_sorted[pos] = s;
    coeff_sorted[pos] = rno[(size_t)r * NN + s] * rni[(size_t)r * NN + d];
}

// sum biases across relations
__global__ void bsum_kernel(const float* __restrict__ b1, const float* __restrict__ b2,
                            float* __restrict__ bsum1, float* __restrict__ bsum2) {
    int t = threadIdx.x;
    if (t < HF) {
        float s = 0.f;
        for (int r = 0; r < NR; r++) s += b1[r * HF + t];
        bsum1[t] = s;
    } else if (t < HF + OUTF) {
        int f = t - HF;
        float s = 0.f;
        for (int r = 0; r < NR; r++) s += b2[r * OUTF + f];
        bsum2[f] = s;
    }
}

// ---------------- conversions -------------------------------------------
__global__ void conv_x_kernel(const float* __restrict__ x, __hip_bfloat16* __restrict__ xb,
                              int total8) {
    int i = blockIdx.x * blockDim.x + threadIdx.x;
    if (i >= total8) return;
    float4 a = ((const float4*)x)[(size_t)i * 2];
    float4 b = ((const float4*)x)[(size_t)i * 2 + 1];
    __hip_bfloat162 o[4];
    o[0] = __float22bfloat162_rn(make_float2(a.x, a.y));
    o[1] = __float22bfloat162_rn(make_float2(a.z, a.w));
    o[2] = __float22bfloat162_rn(make_float2(b.x, b.y));
    o[3] = __float22bfloat162_rn(make_float2(b.z, b.w));
    *(uint4*)(xb + (size_t)i * 8) = *(uint4*)o;
}

// Wt1[r][n][k] = bf16(W1[r][k][n]); Wt2[r][n][k] = bf16(W2[r][k][n])
__global__ void conv_w_kernel(const float* __restrict__ W1, const float* __restrict__ W2,
                              __hip_bfloat16* __restrict__ Wt1, __hip_bfloat16* __restrict__ Wt2) {
    int id = blockIdx.x * blockDim.x + threadIdx.x;
    if (id < NR * HF * INF) {                      // 65536
        int r = id >> 14, rem = id & 16383;
        int n_ = rem >> 7, k = rem & 127;
        Wt1[id] = __float2bfloat16(W1[((size_t)r * INF + k) * HF + n_]);
    } else {
        int id2 = id - NR * HF * INF;
        if (id2 < NR * OUTF * HF) {                // 32768
            int r = id2 >> 13, rem = id2 & 8191;
            int n_ = rem >> 7, k = rem & 127;
            Wt2[id2] = __float2bfloat16(W2[((size_t)r * HF + k) * OUTF + n_]);
        }
    }
}

// ---------------- bf16 MFMA GEMM: Zb[rel][N][F] = Xb[N,128] @ Wt[rel][F,128]^T
// block 256 = 4 waves; wave does 16 rows x F cols; block 64 rows; grid.y = rels
template<int F>
__global__ __launch_bounds__(256) void gemm_mfma(const __hip_bfloat16* __restrict__ Xb,
                                                 const __hip_bfloat16* __restrict__ Wt,
                                                 __hip_bfloat16* __restrict__ Zb) {
    constexpr int NT = F / 16;
    int rel = blockIdx.y;
    const __hip_bfloat16* W = Wt + (size_t)rel * F * 128;
    __hip_bfloat16* Z = Zb + (size_t)rel * NN * F;

    int wid  = threadIdx.x >> 6;
    int lane = threadIdx.x & 63;
    int quad = lane >> 4;
    int l16  = lane & 15;
    int mw   = blockIdx.x * 64 + wid * 16;        // wave row base
    int mrow = mw + l16; if (mrow >= NN) mrow = NN - 1;

    // A fragments: A[m=l16][k = kb*32 + quad*8 + j], 16B loads
    s16x8 afr[4];
    #pragma unroll
    for (int kb = 0; kb < 4; kb++)
        afr[kb] = *(const s16x8*)(Xb + (size_t)mrow * 128 + kb * 32 + quad * 8);

    f32x4 acc[NT];
    #pragma unroll
    for (int nt = 0; nt < NT; nt++) {
        acc[nt] = (f32x4){0.f, 0.f, 0.f, 0.f};
        #pragma unroll
        for (int kb = 0; kb < 4; kb++) {
            // B[k][n=l16] = Wt[n][k] contiguous in k: 16B load
            s16x8 bfr = *(const s16x8*)(W + (size_t)(nt * 16 + l16) * 128 + kb * 32 + quad * 8);
            acc[nt] = __builtin_amdgcn_mfma_f32_16x16x32_bf16(afr[kb], bfr, acc[nt], 0, 0, 0);
        }
    }

    // epilogue: LDS transpose -> coalesced 16B stores. D: row=quad*4+reg, col=nt*16+l16
    __shared__ __hip_bfloat16 lds[4][16][F];
    #pragma unroll
    for (int nt = 0; nt < NT; nt++)
        #pragma unroll
        for (int reg = 0; reg < 4; reg++)
            lds[wid][quad * 4 + reg][nt * 16 + l16] = __float2bfloat16(acc[nt][reg]);
    __syncthreads();

    constexpr int PASSES = (16 * F * 2) / 1024;   // 4 (F=128) or 2 (F=64)
    const char* lbase = (const char*)&lds[wid][0][0];
    #pragma unroll
    for (int p = 0; p < PASSES; p++) {
        int off = lane * 16 + p * 1024;
        int row = off / (F * 2);
        int cb  = off % (F * 2);
        int g = mw + row;
        if (g < NN)
            *(uint4*)((char*)Z + (size_t)g * F * 2 + cb) = *(const uint4*)(lbase + off);
    }
}

// ---------------- fused CSR gather over relations [r0..r1] ---------------
// one wave per dst node; fp32 accumulate; bf16 Z reads
template<int F, bool FIRST, bool RELU, bool OUT_F32>
__global__ void gather_fused(const int* __restrict__ row_ptr, const int* __restrict__ ssrc,
                             const float* __restrict__ scoef, const __hip_bfloat16* __restrict__ Zb,
                             float* __restrict__ outf, __hip_bfloat16* __restrict__ outb,
                             const float* __restrict__ bsum, int r0, int r1) {
    int wid  = threadIdx.x >> 6;
    int lane = threadIdx.x & 63;
    int n = blockIdx.x * (blockDim.x >> 6) + wid;
    if (n >= NN) return;

    if constexpr (F == 128) {
        float2 a;
        if constexpr (FIRST) a = *(const float2*)(bsum + lane * 2);
        else {
            __hip_bfloat162 hv = *(const __hip_bfloat162*)(outb + (size_t)n * 128 + lane * 2);
            a = __bfloat1622float2(hv);
        }
        for (int r = r0; r <= r1; r++) {
            const __hip_bfloat16* Zr = Zb + (size_t)(r - r0) * NN * 128;
            int beg = row_ptr[r * NN + n];
            int end = row_ptr[r * NN + n + 1];
            for (int p = beg; p < end; p++) {
                int s = ssrc[p];
                float c = scoef[p];
                __hip_bfloat162 zv = *(const __hip_bfloat162*)(Zr + (size_t)s * 128 + lane * 2);
                float2 z = __bfloat1622float2(zv);
                a.x = fmaf(c, z.x, a.x);
                a.y = fmaf(c, z.y, a.y);
            }
        }
        if constexpr (RELU) { a.x = fmaxf(a.x, 0.f); a.y = fmaxf(a.y, 0.f); }
        *(__hip_bfloat162*)(outb + (size_t)n * 128 + lane * 2) = __float22bfloat162_rn(a);
    } else {
        float a = FIRST ? bsum[lane] : 0.f;
        for (int r = r0; r <= r1; r++) {
            const __hip_bfloat16* Zr = Zb + (size_t)(r - r0) * NN * 64;
            int beg = row_ptr[r * NN + n];
            int end = row_ptr[r * NN + n + 1];
            for (int p = beg; p < end; p++) {
                int s = ssrc[p];
                float c = scoef[p];
                a = fmaf(c, __bfloat162float(Zr[(size_t)s * 64 + lane]), a);
            }
        }
        if constexpr (RELU) a = fmaxf(a, 0.f);
        if constexpr (OUT_F32) outf[(size_t)n * 64 + lane] = a;
        else outb[(size_t)n * 64 + lane] = __float2bfloat16(a);
    }
}

extern "C" void kernel_launch(void* const* d_in, const int* in_sizes, int n_in,
                              void* d_out, int out_size, void* d_ws, size_t ws_size,
                              hipStream_t stream) {
    const float* x   = (const float*)d_in[0];
    const int*   src = (const int*)  d_in[1];   // [4, 400000]
    const int*   dst = (const int*)  d_in[2];
    const float* W1  = (const float*)d_in[3];   // [4,128,128]
    const float* b1  = (const float*)d_in[4];   // [4,128]
    const float* W2  = (const float*)d_in[5];   // [4,128,64]
    const float* b2  = (const float*)d_in[6];   // [4,64]
    float* out = (float*)d_out;                 // [100000,64] fp32

    constexpr int RN = NR * NN;                 // 400000 rows total
    constexpr int NB = (RN + 1023) / 1024;

    char* p = (char*)d_ws;
    int*   deg_out_i = (int*)p;   p += (size_t)RN * 4;
    int*   deg_in_i  = (int*)p;   p += (size_t)RN * 4;
    float* rno       = (float*)p; p += (size_t)RN * 4;
    float* rni       = (float*)p; p += (size_t)RN * 4;
    int*   row_ptr   = (int*)p;   p += ((size_t)RN + 16) * 4;
    int*   cursor    = (int*)p;   p += (size_t)RN * 4;
    int*   blockSums = (int*)p;   p += 1024 * 4;
    int*   src_sorted   = (int*)p;   p += (size_t)NR * NE * 4;
    float* coeff_sorted = (float*)p; p += (size_t)NR * NE * 4;
    float* bsum1 = (float*)p; p += HF * 4;
    float* bsum2 = (float*)p; p += OUTF * 4;
    __hip_bfloat16* xb  = (__hip_bfloat16*)p; p += (size_t)NN * INF * 2;   // 25.6 MB
    __hip_bfloat16* hb  = (__hip_bfloat16*)p; p += (size_t)NN * HF * 2;    // 25.6 MB
    __hip_bfloat16* Wt1 = (__hip_bfloat16*)p; p += (size_t)NR * HF * INF * 2;
    __hip_bfloat16* Wt2 = (__hip_bfloat16*)p; p += (size_t)NR * OUTF * HF * 2;
    __hip_bfloat16* Zb  = (__hip_bfloat16*)p; p += (size_t)2 * NN * HF * 2; // 51.2 MB

    // ---- CSR build (reused by both layers) ----
    hipMemsetAsync(deg_out_i, 0, (size_t)2 * RN * 4, stream);
    deg_kernel<<<dim3((NE + 255) / 256, NR), 256, 0, stream>>>(src, dst, deg_out_i, deg_in_i);
    norm_kernel<<<(RN + 255) / 256, 256, 0, stream>>>(deg_out_i, deg_in_i, rno, rni, RN);
    scan_block_kernel<<<NB, 256, 0, stream>>>(deg_in_i, row_ptr, blockSums, RN);
    scan_sums_kernel<<<1, 512, 0, stream>>>(blockSums, NB);
    scan_add_kernel<<<(RN + 255) / 256, 256, 0, stream>>>(row_ptr, blockSums, cursor, RN);
    csr_build_kernel<<<dim3((NE + 255) / 256, NR), 256, 0, stream>>>(
        src, dst, rno, rni, cursor, src_sorted, coeff_sorted);
    bsum_kernel<<<1, 192, 0, stream>>>(b1, b2, bsum1, bsum2);

    // ---- conversions ----
    conv_x_kernel<<<(NN * INF / 8 + 255) / 256, 256, 0, stream>>>(x, xb, NN * INF / 8);
    conv_w_kernel<<<(NR * HF * INF + NR * OUTF * HF + 255) / 256, 256, 0, stream>>>(W1, W2, Wt1, Wt2);

    // ---- layer 1: hb = relu( sum_r gather_r(xb @ W1_r) + bsum1 ), 2 groups of 2 rels
    constexpr int GB = (NN + 63) / 64;   // 1563
    constexpr int GG = (NN + 3) / 4;     // 25000
    for (int g = 0; g < 2; g++) {
        gemm_mfma<HF><<<dim3(GB, 2), 256, 0, stream>>>(xb, Wt1 + (size_t)g * 2 * HF * INF, Zb);
        if (g == 0)
            gather_fused<HF, true, false, false><<<GG, 256, 0, stream>>>(
                row_ptr, src_sorted, coeff_sorted, Zb, nullptr, hb, bsum1, 0, 1);
        else
            gather_fused<HF, false, true, false><<<GG, 256, 0, stream>>>(
                row_ptr, src_sorted, coeff_sorted, Zb, nullptr, hb, bsum1, 2, 3);
    }

    // ---- layer 2: out = sum_r gather_r(hb @ W2_r) + bsum2, all 4 rels ----
    gemm_mfma<OUTF><<<dim3(GB, 4), 256, 0, stream>>>(hb, Wt2, Zb);
    gather_fused<OUTF, true, false, true><<<GG, 256, 0, stream>>>(
        row_ptr, src_sorted, coeff_sorted, Zb, out, nullptr, bsum2, 0, 3);
}

// Round 4
// 742.915 us; speedup vs baseline: 3.2000x; 1.1543x over previous
//
#include <hip/hip_runtime.h>
#include <hip/hip_bf16.h>

#define NN 100000      // nodes
#define NR 4           // relations
#define NE 400000      // edges per relation
#define INF 128
#define HF 128
#define OUTF 64
#define HC 8           // histogram copies (contention reduction)

typedef __attribute__((ext_vector_type(8))) short s16x8;   // 8 bf16 (4 VGPRs)
typedef __attribute__((ext_vector_type(4))) float f32x4;   // MFMA C/D

// ---------------- int degree histogram, HC copies ------------------------
// degm layout: [HC][RN] out-copies then [HC][RN] in-copies
__global__ void deg_kernel(const int* __restrict__ src, const int* __restrict__ dst,
                           int* __restrict__ degm) {
    constexpr int RN = NR * NN;
    int r = blockIdx.y;
    int i = blockIdx.x * blockDim.x + threadIdx.x;
    if (i >= NE) return;
    int c = blockIdx.x & (HC - 1);
    int s = src[(size_t)r * NE + i];
    int d = dst[(size_t)r * NE + i];
    atomicAdd(&degm[(size_t)c * RN + r * NN + s], 1);
    atomicAdd(&degm[(size_t)(HC + c) * RN + r * NN + d], 1);
}

// reduce copies -> deg_in (for scan) + rsqrt norms
__global__ void red_norm_kernel(const int* __restrict__ degm, int* __restrict__ deg_in_i,
                                float* __restrict__ rno, float* __restrict__ rni) {
    constexpr int RN = NR * NN;
    int i = blockIdx.x * blockDim.x + threadIdx.x;
    if (i >= RN) return;
    int so = 0, si = 0;
    #pragma unroll
    for (int c = 0; c < HC; c++) {
        so += degm[(size_t)c * RN + i];
        si += degm[(size_t)(HC + c) * RN + i];
    }
    deg_in_i[i] = si;
    rno[i] = rsqrtf(fmaxf((float)so, 1.0f));
    rni[i] = rsqrtf(fmaxf((float)si, 1.0f));
}

// ---------------- exclusive scan over deg_in (NR*NN entries) -------------
__global__ void scan_block_kernel(const int* __restrict__ in, int* __restrict__ out,
                                  int* __restrict__ blockSums, int n) {
    __shared__ int sd[256];
    int t = threadIdx.x;
    int base = blockIdx.x * 1024 + t * 4;
    int v[4];
    #pragma unroll
    for (int j = 0; j < 4; j++) v[j] = (base + j < n) ? in[base + j] : 0;
    int ts = v[0] + v[1] + v[2] + v[3];
    sd[t] = ts;
    __syncthreads();
    int acc = ts;
    for (int off = 1; off < 256; off <<= 1) {
        int x = (t >= off) ? sd[t - off] : 0;
        __syncthreads();
        acc += x; sd[t] = acc;
        __syncthreads();
    }
    int run = acc - ts;
    #pragma unroll
    for (int j = 0; j < 4; j++) {
        if (base + j < n) out[base + j] = run;
        run += v[j];
    }
    if (t == 255) blockSums[blockIdx.x] = acc;
}

__global__ void scan_sums_kernel(int* __restrict__ blockSums, int nb) {
    __shared__ int sd[512];
    int t = threadIdx.x;
    int v = (t < nb) ? blockSums[t] : 0;
    sd[t] = v;
    __syncthreads();
    int acc = v;
    for (int off = 1; off < 512; off <<= 1) {
        int x = (t >= off) ? sd[t - off] : 0;
        __syncthreads();
        acc += x; sd[t] = acc;
        __syncthreads();
    }
    if (t < nb) blockSums[t] = acc - v;
}

__global__ void scan_add_kernel(int* __restrict__ row_ptr, const int* __restrict__ blockSums,
                                int* __restrict__ cursor, int n) {
    int i = blockIdx.x * blockDim.x + threadIdx.x;
    if (i < n) {
        int v = row_ptr[i] + blockSums[i >> 10];
        row_ptr[i] = v;
        cursor[i] = v;
    }
    if (i == 0) row_ptr[n] = NR * NE;
}

// ---------------- CSR build: scatter (src, coeff) into dst-sorted order --
__global__ void csr_build_kernel(const int* __restrict__ src, const int* __restrict__ dst,
                                 const float* __restrict__ rno, const float* __restrict__ rni,
                                 int* __restrict__ cursor, int* __restrict__ src_sorted,
                                 float* __restrict__ coeff_sorted) {
    int r = blockIdx.y;
    int i = blockIdx.x * blockDim.x + threadIdx.x;
    if (i >= NE) return;
    int s = src[(size_t)r * NE + i];
    int d = dst[(size_t)r * NE + i];
    int pos = atomicAdd(&cursor[(size_t)r * NN + d], 1);
    src_sorted[pos] = s;
    coeff_sorted[pos] = rno[(size_t)r * NN + s] * rni[(size_t)r * NN + d];
}

// sum biases across relations
__global__ void bsum_kernel(const float* __restrict__ b1, const float* __restrict__ b2,
                            float* __restrict__ bsum1, float* __restrict__ bsum2) {
    int t = threadIdx.x;
    if (t < HF) {
        float s = 0.f;
        for (int r = 0; r < NR; r++) s += b1[r * HF + t];
        bsum1[t] = s;
    } else if (t < HF + OUTF) {
        int f = t - HF;
        float s = 0.f;
        for (int r = 0; r < NR; r++) s += b2[r * OUTF + f];
        bsum2[f] = s;
    }
}

// ---------------- conversions -------------------------------------------
__global__ void conv_x_kernel(const float* __restrict__ x, __hip_bfloat16* __restrict__ xb,
                              int total8) {
    int i = blockIdx.x * blockDim.x + threadIdx.x;
    if (i >= total8) return;
    float4 a = ((const float4*)x)[(size_t)i * 2];
    float4 b = ((const float4*)x)[(size_t)i * 2 + 1];
    __hip_bfloat162 o[4];
    o[0] = __float22bfloat162_rn(make_float2(a.x, a.y));
    o[1] = __float22bfloat162_rn(make_float2(a.z, a.w));
    o[2] = __float22bfloat162_rn(make_float2(b.x, b.y));
    o[3] = __float22bfloat162_rn(make_float2(b.z, b.w));
    *(uint4*)(xb + (size_t)i * 8) = *(uint4*)o;
}

// Wt1[r][n][k] = bf16(W1[r][k][n]); Wt2[r][n][k] = bf16(W2[r][k][n])
__global__ void conv_w_kernel(const float* __restrict__ W1, const float* __restrict__ W2,
                              __hip_bfloat16* __restrict__ Wt1, __hip_bfloat16* __restrict__ Wt2) {
    int id = blockIdx.x * blockDim.x + threadIdx.x;
    if (id < NR * HF * INF) {                      // 65536
        int r = id >> 14, rem = id & 16383;
        int n_ = rem >> 7, k = rem & 127;
        Wt1[id] = __float2bfloat16(W1[((size_t)r * INF + k) * HF + n_]);
    } else {
        int id2 = id - NR * HF * INF;
        if (id2 < NR * OUTF * HF) {                // 32768
            int r = id2 >> 13, rem = id2 & 8191;
            int n_ = rem >> 7, k = rem & 127;
            Wt2[id2] = __float2bfloat16(W2[((size_t)r * HF + k) * OUTF + n_]);
        }
    }
}

// ---------------- bf16 MFMA GEMM: Zb[rel][N][F] = Xb[N,128] @ Wt[rel][F,128]^T
template<int F>
__global__ __launch_bounds__(256) void gemm_mfma(const __hip_bfloat16* __restrict__ Xb,
                                                 const __hip_bfloat16* __restrict__ Wt,
                                                 __hip_bfloat16* __restrict__ Zb) {
    constexpr int NT = F / 16;
    int rel = blockIdx.y;
    const __hip_bfloat16* W = Wt + (size_t)rel * F * 128;
    __hip_bfloat16* Z = Zb + (size_t)rel * NN * F;

    int wid  = threadIdx.x >> 6;
    int lane = threadIdx.x & 63;
    int quad = lane >> 4;
    int l16  = lane & 15;
    int mw   = blockIdx.x * 64 + wid * 16;
    int mrow = mw + l16; if (mrow >= NN) mrow = NN - 1;

    s16x8 afr[4];
    #pragma unroll
    for (int kb = 0; kb < 4; kb++)
        afr[kb] = *(const s16x8*)(Xb + (size_t)mrow * 128 + kb * 32 + quad * 8);

    f32x4 acc[NT];
    #pragma unroll
    for (int nt = 0; nt < NT; nt++) {
        acc[nt] = (f32x4){0.f, 0.f, 0.f, 0.f};
        #pragma unroll
        for (int kb = 0; kb < 4; kb++) {
            s16x8 bfr = *(const s16x8*)(W + (size_t)(nt * 16 + l16) * 128 + kb * 32 + quad * 8);
            acc[nt] = __builtin_amdgcn_mfma_f32_16x16x32_bf16(afr[kb], bfr, acc[nt], 0, 0, 0);
        }
    }

    __shared__ __hip_bfloat16 lds[4][16][F];
    #pragma unroll
    for (int nt = 0; nt < NT; nt++)
        #pragma unroll
        for (int reg = 0; reg < 4; reg++)
            lds[wid][quad * 4 + reg][nt * 16 + l16] = __float2bfloat16(acc[nt][reg]);
    __syncthreads();

    constexpr int PASSES = (16 * F * 2) / 1024;
    const char* lbase = (const char*)&lds[wid][0][0];
    #pragma unroll
    for (int p = 0; p < PASSES; p++) {
        int off = lane * 16 + p * 1024;
        int row = off / (F * 2);
        int cb  = off % (F * 2);
        int g = mw + row;
        if (g < NN)
            *(uint4*)((char*)Z + (size_t)g * F * 2 + cb) = *(const uint4*)(lbase + off);
    }
}

// ---------------- fused CSR gather, 4-wide MLP unrolled ------------------
// one wave per dst node; clamped 4-wide chunks: OOB -> src=s0 (same line,
// near-free) with coeff=0; gives 4 independent gathers in flight per wave.
template<int F, bool FIRST, bool RELU, bool OUT_F32>
__global__ void gather_fused(const int* __restrict__ row_ptr, const int* __restrict__ ssrc,
                             const float* __restrict__ scoef, const __hip_bfloat16* __restrict__ Zb,
                             float* __restrict__ outf, __hip_bfloat16* __restrict__ outb,
                             const float* __restrict__ bsum, int r0, int r1) {
    int wid  = threadIdx.x >> 6;
    int lane = threadIdx.x & 63;
    int n = blockIdx.x * (blockDim.x >> 6) + wid;
    if (n >= NN) return;

    if constexpr (F == 128) {
        float2 a;
        if constexpr (FIRST) a = *(const float2*)(bsum + lane * 2);
        else {
            __hip_bfloat162 hv = *(const __hip_bfloat162*)(outb + (size_t)n * 128 + lane * 2);
            a = __bfloat1622float2(hv);
        }
        for (int r = r0; r <= r1; r++) {
            const __hip_bfloat16* Zr = Zb + (size_t)(r - r0) * NN * 128;
            int beg = row_ptr[r * NN + n];
            int end = row_ptr[r * NN + n + 1];
            for (int p = beg; p < end; p += 4) {
                int rem = end - p;
                int   s0 = ssrc[p];
                float c0 = scoef[p];
                int   s1 = (rem > 1) ? ssrc[p + 1]  : s0;
                float c1 = (rem > 1) ? scoef[p + 1] : 0.f;
                int   s2 = (rem > 2) ? ssrc[p + 2]  : s0;
                float c2 = (rem > 2) ? scoef[p + 2] : 0.f;
                int   s3 = (rem > 3) ? ssrc[p + 3]  : s0;
                float c3 = (rem > 3) ? scoef[p + 3] : 0.f;
                float2 z0 = __bfloat1622float2(*(const __hip_bfloat162*)(Zr + (size_t)s0 * 128 + lane * 2));
                float2 z1 = __bfloat1622float2(*(const __hip_bfloat162*)(Zr + (size_t)s1 * 128 + lane * 2));
                float2 z2 = __bfloat1622float2(*(const __hip_bfloat162*)(Zr + (size_t)s2 * 128 + lane * 2));
                float2 z3 = __bfloat1622float2(*(const __hip_bfloat162*)(Zr + (size_t)s3 * 128 + lane * 2));
                a.x = fmaf(c0, z0.x, fmaf(c1, z1.x, fmaf(c2, z2.x, fmaf(c3, z3.x, a.x))));
                a.y = fmaf(c0, z0.y, fmaf(c1, z1.y, fmaf(c2, z2.y, fmaf(c3, z3.y, a.y))));
            }
        }
        if constexpr (RELU) { a.x = fmaxf(a.x, 0.f); a.y = fmaxf(a.y, 0.f); }
        *(__hip_bfloat162*)(outb + (size_t)n * 128 + lane * 2) = __float22bfloat162_rn(a);
    } else {
        float a = FIRST ? bsum[lane] : 0.f;
        for (int r = r0; r <= r1; r++) {
            const __hip_bfloat16* Zr = Zb + (size_t)(r - r0) * NN * 64;
            int beg = row_ptr[r * NN + n];
            int end = row_ptr[r * NN + n + 1];
            for (int p = beg; p < end; p += 4) {
                int rem = end - p;
                int   s0 = ssrc[p];
                float c0 = scoef[p];
                int   s1 = (rem > 1) ? ssrc[p + 1]  : s0;
                float c1 = (rem > 1) ? scoef[p + 1] : 0.f;
                int   s2 = (rem > 2) ? ssrc[p + 2]  : s0;
                float c2 = (rem > 2) ? scoef[p + 2] : 0.f;
                int   s3 = (rem > 3) ? ssrc[p + 3]  : s0;
                float c3 = (rem > 3) ? scoef[p + 3] : 0.f;
                float z0 = __bfloat162float(Zr[(size_t)s0 * 64 + lane]);
                float z1 = __bfloat162float(Zr[(size_t)s1 * 64 + lane]);
                float z2 = __bfloat162float(Zr[(size_t)s2 * 64 + lane]);
                float z3 = __bfloat162float(Zr[(size_t)s3 * 64 + lane]);
                a = fmaf(c0, z0, fmaf(c1, z1, fmaf(c2, z2, fmaf(c3, z3, a))));
            }
        }
        if constexpr (RELU) a = fmaxf(a, 0.f);
        if constexpr (OUT_F32) outf[(size_t)n * 64 + lane] = a;
        else outb[(size_t)n * 64 + lane] = __float2bfloat16(a);
    }
}

extern "C" void kernel_launch(void* const* d_in, const int* in_sizes, int n_in,
                              void* d_out, int out_size, void* d_ws, size_t ws_size,
                              hipStream_t stream) {
    const float* x   = (const float*)d_in[0];
    const int*   src = (const int*)  d_in[1];   // [4, 400000]
    const int*   dst = (const int*)  d_in[2];
    const float* W1  = (const float*)d_in[3];   // [4,128,128]
    const float* b1  = (const float*)d_in[4];   // [4,128]
    const float* W2  = (const float*)d_in[5];   // [4,128,64]
    const float* b2  = (const float*)d_in[6];   // [4,64]
    float* out = (float*)d_out;                 // [100000,64] fp32

    constexpr int RN = NR * NN;                 // 400000 rows total
    constexpr int NB = (RN + 1023) / 1024;

    char* p = (char*)d_ws;
    int*   deg_in_i  = (int*)p;   p += (size_t)RN * 4;
    float* rno       = (float*)p; p += (size_t)RN * 4;
    float* rni       = (float*)p; p += (size_t)RN * 4;
    int*   row_ptr   = (int*)p;   p += ((size_t)RN + 16) * 4;
    int*   cursor    = (int*)p;   p += (size_t)RN * 4;
    int*   blockSums = (int*)p;   p += 1024 * 4;
    int*   src_sorted   = (int*)p;   p += (size_t)NR * NE * 4;
    float* coeff_sorted = (float*)p; p += (size_t)NR * NE * 4;
    float* bsum1 = (float*)p; p += HF * 4;
    float* bsum2 = (float*)p; p += OUTF * 4;
    __hip_bfloat16* xb  = (__hip_bfloat16*)p; p += (size_t)NN * INF * 2;   // 25.6 MB
    __hip_bfloat16* hb  = (__hip_bfloat16*)p; p += (size_t)NN * HF * 2;    // 25.6 MB
    __hip_bfloat16* Wt1 = (__hip_bfloat16*)p; p += (size_t)NR * HF * INF * 2;
    __hip_bfloat16* Wt2 = (__hip_bfloat16*)p; p += (size_t)NR * OUTF * HF * 2;
    __hip_bfloat16* Zb  = (__hip_bfloat16*)p; p += (size_t)2 * NN * HF * 2; // 51.2 MB
    int* degm = (int*)Zb;   // [2*HC][RN] ints = 25.6 MB, dead before Zb is written

    // ---- CSR build (reused by both layers) ----
    hipMemsetAsync(degm, 0, (size_t)2 * HC * RN * 4, stream);
    deg_kernel<<<dim3((NE + 255) / 256, NR), 256, 0, stream>>>(src, dst, degm);
    red_norm_kernel<<<(RN + 255) / 256, 256, 0, stream>>>(degm, deg_in_i, rno, rni);
    scan_block_kernel<<<NB, 256, 0, stream>>>(deg_in_i, row_ptr, blockSums, RN);
    scan_sums_kernel<<<1, 512, 0, stream>>>(blockSums, NB);
    scan_add_kernel<<<(RN + 255) / 256, 256, 0, stream>>>(row_ptr, blockSums, cursor, RN);
    csr_build_kernel<<<dim3((NE + 255) / 256, NR), 256, 0, stream>>>(
        src, dst, rno, rni, cursor, src_sorted, coeff_sorted);
    bsum_kernel<<<1, 192, 0, stream>>>(b1, b2, bsum1, bsum2);

    // ---- conversions ----
    conv_x_kernel<<<(NN * INF / 8 + 255) / 256, 256, 0, stream>>>(x, xb, NN * INF / 8);
    conv_w_kernel<<<(NR * HF * INF + NR * OUTF * HF + 255) / 256, 256, 0, stream>>>(W1, W2, Wt1, Wt2);

    // ---- layer 1: hb = relu( sum_r gather_r(xb @ W1_r) + bsum1 ), 2 groups of 2 rels
    constexpr int GB = (NN + 63) / 64;   // 1563
    constexpr int GG = (NN + 3) / 4;     // 25000
    for (int g = 0; g < 2; g++) {
        gemm_mfma<HF><<<dim3(GB, 2), 256, 0, stream>>>(xb, Wt1 + (size_t)g * 2 * HF * INF, Zb);
        if (g == 0)
            gather_fused<HF, true, false, false><<<GG, 256, 0, stream>>>(
                row_ptr, src_sorted, coeff_sorted, Zb, nullptr, hb, bsum1, 0, 1);
        else
            gather_fused<HF, false, true, false><<<GG, 256, 0, stream>>>(
                row_ptr, src_sorted, coeff_sorted, Zb, nullptr, hb, bsum1, 2, 3);
    }

    // ---- layer 2: out = sum_r gather_r(hb @ W2_r) + bsum2, all 4 rels ----
    gemm_mfma<OUTF><<<dim3(GB, 4), 256, 0, stream>>>(hb, Wt2, Zb);
    gather_fused<OUTF, true, false, true><<<GG, 256, 0, stream>>>(
        row_ptr, src_sorted, coeff_sorted, Zb, out, nullptr, bsum2, 0, 3);
}

// Round 5
// 717.072 us; speedup vs baseline: 3.3154x; 1.0360x over previous
//
#include <hip/hip_runtime.h>
#include <hip/hip_bf16.h>

#define NN 100000      // nodes
#define NR 4           // relations
#define NE 400000      // edges per relation
#define INF 128
#define HF 128
#define OUTF 64

#define WIN 8192       // histogram window (32 KB LDS)
#define NWIN 13        // ceil(NN / WIN)
#define SUB 8          // edge-slices per window
#define SLICE (NE / SUB)

typedef __attribute__((ext_vector_type(8))) short s16x8;   // 8 bf16 (4 VGPRs)
typedef __attribute__((ext_vector_type(4))) float f32x4;   // MFMA C/D

// ---------------- windowed LDS degree histogram (no global atomics) ------
// grid: (NWIN*SUB, NR, 2); z=0: src->deg_out partials, z=1: dst->deg_in
__global__ __launch_bounds__(256) void deg_win_kernel(const int* __restrict__ src,
                                                      const int* __restrict__ dst,
                                                      int* __restrict__ parts) {
    __shared__ int hist[WIN];
    int arr = blockIdx.z;
    int r   = blockIdx.y;
    int win = blockIdx.x / SUB;
    int sub = blockIdx.x % SUB;
    const int* idx = (arr ? dst : src) + (size_t)r * NE + (size_t)sub * SLICE;
    int base = win * WIN;
    for (int i = threadIdx.x; i < WIN; i += 256) hist[i] = 0;
    __syncthreads();
    for (int i = threadIdx.x; i < SLICE; i += 256) {
        int v = idx[i] - base;
        if ((unsigned)v < WIN) atomicAdd(&hist[v], 1);
    }
    __syncthreads();
    int* outp = parts + ((((size_t)arr * NR + r) * NWIN + win) * SUB + sub) * WIN;
    for (int i = threadIdx.x; i < WIN; i += 256) outp[i] = hist[i];
}

// reduce partials -> deg_in (for scan) + rsqrt norms
__global__ void red_norm_kernel(const int* __restrict__ parts, int* __restrict__ deg_in_i,
                                float* __restrict__ rno, float* __restrict__ rni) {
    int i = blockIdx.x * blockDim.x + threadIdx.x;
    if (i >= NR * NN) return;
    int r = i / NN, n = i % NN;
    int win = n / WIN, off = n % WIN;
    const int* p0 = parts + (((size_t)0 * NR + r) * NWIN + win) * SUB * WIN + off;
    const int* p1 = parts + (((size_t)1 * NR + r) * NWIN + win) * SUB * WIN + off;
    int so = 0, si = 0;
    #pragma unroll
    for (int s = 0; s < SUB; s++) { so += p0[(size_t)s * WIN]; si += p1[(size_t)s * WIN]; }
    deg_in_i[i] = si;
    rno[i] = rsqrtf(fmaxf((float)so, 1.0f));
    rni[i] = rsqrtf(fmaxf((float)si, 1.0f));
}

// ---------------- exclusive scan over deg_in (NR*NN entries) -------------
__global__ void scan_block_kernel(const int* __restrict__ in, int* __restrict__ out,
                                  int* __restrict__ blockSums, int n) {
    __shared__ int sd[256];
    int t = threadIdx.x;
    int base = blockIdx.x * 1024 + t * 4;
    int v[4];
    #pragma unroll
    for (int j = 0; j < 4; j++) v[j] = (base + j < n) ? in[base + j] : 0;
    int ts = v[0] + v[1] + v[2] + v[3];
    sd[t] = ts;
    __syncthreads();
    int acc = ts;
    for (int off = 1; off < 256; off <<= 1) {
        int x = (t >= off) ? sd[t - off] : 0;
        __syncthreads();
        acc += x; sd[t] = acc;
        __syncthreads();
    }
    int run = acc - ts;
    #pragma unroll
    for (int j = 0; j < 4; j++) {
        if (base + j < n) out[base + j] = run;
        run += v[j];
    }
    if (t == 255) blockSums[blockIdx.x] = acc;
}

__global__ void scan_sums_kernel(int* __restrict__ blockSums, int nb) {
    __shared__ int sd[512];
    int t = threadIdx.x;
    int v = (t < nb) ? blockSums[t] : 0;
    sd[t] = v;
    __syncthreads();
    int acc = v;
    for (int off = 1; off < 512; off <<= 1) {
        int x = (t >= off) ? sd[t - off] : 0;
        __syncthreads();
        acc += x; sd[t] = acc;
        __syncthreads();
    }
    if (t < nb) blockSums[t] = acc - v;
}

__global__ void scan_add_kernel(int* __restrict__ row_ptr, const int* __restrict__ blockSums,
                                int* __restrict__ cursor, int n) {
    int i = blockIdx.x * blockDim.x + threadIdx.x;
    if (i < n) {
        int v = row_ptr[i] + blockSums[i >> 10];
        row_ptr[i] = v;
        cursor[i] = v;
    }
    if (i == 0) row_ptr[n] = NR * NE;
}

// ---------------- CSR build: scatter (src,coeff) int2 into dst-sorted ----
__global__ void csr_build_kernel(const int* __restrict__ src, const int* __restrict__ dst,
                                 const float* __restrict__ rno, const float* __restrict__ rni,
                                 int* __restrict__ cursor, int2* __restrict__ edges) {
    int r = blockIdx.y;
    int i = blockIdx.x * blockDim.x + threadIdx.x;
    if (i >= NE) return;
    int s = src[(size_t)r * NE + i];
    int d = dst[(size_t)r * NE + i];
    int pos = atomicAdd(&cursor[(size_t)r * NN + d], 1);
    float c = rno[(size_t)r * NN + s] * rni[(size_t)r * NN + d];
    edges[pos] = make_int2(s, __float_as_int(c));
}

// sum biases across relations
__global__ void bsum_kernel(const float* __restrict__ b1, const float* __restrict__ b2,
                            float* __restrict__ bsum1, float* __restrict__ bsum2) {
    int t = threadIdx.x;
    if (t < HF) {
        float s = 0.f;
        for (int r = 0; r < NR; r++) s += b1[r * HF + t];
        bsum1[t] = s;
    } else if (t < HF + OUTF) {
        int f = t - HF;
        float s = 0.f;
        for (int r = 0; r < NR; r++) s += b2[r * OUTF + f];
        bsum2[f] = s;
    }
}

// Wt1[r][n][k] = bf16(W1[r][k][n]); Wt2[r][n][k] = bf16(W2[r][k][n])
__global__ void conv_w_kernel(const float* __restrict__ W1, const float* __restrict__ W2,
                              __hip_bfloat16* __restrict__ Wt1, __hip_bfloat16* __restrict__ Wt2) {
    int id = blockIdx.x * blockDim.x + threadIdx.x;
    if (id < NR * HF * INF) {                      // 65536
        int r = id >> 14, rem = id & 16383;
        int n_ = rem >> 7, k = rem & 127;
        Wt1[id] = __float2bfloat16(W1[((size_t)r * INF + k) * HF + n_]);
    } else {
        int id2 = id - NR * HF * INF;
        if (id2 < NR * OUTF * HF) {                // 32768
            int r = id2 >> 13, rem = id2 & 8191;
            int n_ = rem >> 7, k = rem & 127;
            Wt2[id2] = __float2bfloat16(W2[((size_t)r * HF + k) * OUTF + n_]);
        }
    }
}

__device__ __forceinline__ s16x8 pack_bf16x8(float4 a0, float4 a1) {
    union { s16x8 v; __hip_bfloat162 h[4]; } u;
    u.h[0] = __float22bfloat162_rn(make_float2(a0.x, a0.y));
    u.h[1] = __float22bfloat162_rn(make_float2(a0.z, a0.w));
    u.h[2] = __float22bfloat162_rn(make_float2(a1.x, a1.y));
    u.h[3] = __float22bfloat162_rn(make_float2(a1.z, a1.w));
    return u.v;
}

// ---------------- bf16 MFMA GEMM: Zb[rel][N][F] = A[N,128] @ Wt[rel][F,128]^T
// AT = float (inline bf16 convert) or __hip_bfloat16
template<int F, typename AT>
__global__ __launch_bounds__(256) void gemm_mfma(const AT* __restrict__ Xb,
                                                 const __hip_bfloat16* __restrict__ Wt,
                                                 __hip_bfloat16* __restrict__ Zb) {
    constexpr int NT = F / 16;
    int rel = blockIdx.y;
    const __hip_bfloat16* W = Wt + (size_t)rel * F * 128;
    __hip_bfloat16* Z = Zb + (size_t)rel * NN * F;

    int wid  = threadIdx.x >> 6;
    int lane = threadIdx.x & 63;
    int quad = lane >> 4;
    int l16  = lane & 15;
    int mw   = blockIdx.x * 64 + wid * 16;
    int mrow = mw + l16; if (mrow >= NN) mrow = NN - 1;

    s16x8 afr[4];
    #pragma unroll
    for (int kb = 0; kb < 4; kb++) {
        if constexpr (sizeof(AT) == 4) {
            const float* xr = (const float*)Xb + (size_t)mrow * 128 + kb * 32 + quad * 8;
            float4 a0 = *(const float4*)xr;
            float4 a1 = *(const float4*)(xr + 4);
            afr[kb] = pack_bf16x8(a0, a1);
        } else {
            afr[kb] = *(const s16x8*)((const __hip_bfloat16*)Xb + (size_t)mrow * 128 + kb * 32 + quad * 8);
        }
    }

    f32x4 acc[NT];
    #pragma unroll
    for (int nt = 0; nt < NT; nt++) {
        acc[nt] = (f32x4){0.f, 0.f, 0.f, 0.f};
        #pragma unroll
        for (int kb = 0; kb < 4; kb++) {
            s16x8 bfr = *(const s16x8*)(W + (size_t)(nt * 16 + l16) * 128 + kb * 32 + quad * 8);
            acc[nt] = __builtin_amdgcn_mfma_f32_16x16x32_bf16(afr[kb], bfr, acc[nt], 0, 0, 0);
        }
    }

    __shared__ __hip_bfloat16 lds[4][16][F];
    #pragma unroll
    for (int nt = 0; nt < NT; nt++)
        #pragma unroll
        for (int reg = 0; reg < 4; reg++)
            lds[wid][quad * 4 + reg][nt * 16 + l16] = __float2bfloat16(acc[nt][reg]);
    __syncthreads();

    constexpr int PASSES = (16 * F * 2) / 1024;
    const char* lbase = (const char*)&lds[wid][0][0];
    #pragma unroll
    for (int p = 0; p < PASSES; p++) {
        int off = lane * 16 + p * 1024;
        int row = off / (F * 2);
        int cb  = off % (F * 2);
        int g = mw + row;
        if (g < NN)
            *(uint4*)((char*)Z + (size_t)g * F * 2 + cb) = *(const uint4*)(lbase + off);
    }
}

// ---------------- fused CSR gather, 8-wide MLP unrolled ------------------
// one wave per dst node; clamped 8-wide chunks (OOB -> last edge, coeff=0)
template<int F, bool FIRST, bool RELU, bool OUT_F32>
__global__ void gather_fused(const int* __restrict__ row_ptr, const int2* __restrict__ edges,
                             const __hip_bfloat16* __restrict__ Zb,
                             float* __restrict__ outf, __hip_bfloat16* __restrict__ outb,
                             const float* __restrict__ bsum, int r0, int r1) {
    int wid  = threadIdx.x >> 6;
    int lane = threadIdx.x & 63;
    int n = blockIdx.x * (blockDim.x >> 6) + wid;
    if (n >= NN) return;

    if constexpr (F == 128) {
        float2 a;
        if constexpr (FIRST) a = *(const float2*)(bsum + lane * 2);
        else {
            __hip_bfloat162 hv = *(const __hip_bfloat162*)(outb + (size_t)n * 128 + lane * 2);
            a = __bfloat1622float2(hv);
        }
        for (int r = r0; r <= r1; r++) {
            const __hip_bfloat16* Zr = Zb + (size_t)(r - r0) * NN * 128;
            int beg = row_ptr[r * NN + n];
            int end = row_ptr[r * NN + n + 1];
            for (int p = beg; p < end; p += 8) {
                int   ss[8]; float cc[8];
                #pragma unroll
                for (int j = 0; j < 8; j++) {
                    int q = (p + j < end) ? p + j : end - 1;
                    int2 e = edges[q];
                    ss[j] = e.x;
                    cc[j] = (p + j < end) ? __int_as_float(e.y) : 0.f;
                }
                float2 zz[8];
                #pragma unroll
                for (int j = 0; j < 8; j++)
                    zz[j] = __bfloat1622float2(*(const __hip_bfloat162*)(Zr + (size_t)ss[j] * 128 + lane * 2));
                #pragma unroll
                for (int j = 0; j < 8; j++) {
                    a.x = fmaf(cc[j], zz[j].x, a.x);
                    a.y = fmaf(cc[j], zz[j].y, a.y);
                }
            }
        }
        if constexpr (RELU) { a.x = fmaxf(a.x, 0.f); a.y = fmaxf(a.y, 0.f); }
        *(__hip_bfloat162*)(outb + (size_t)n * 128 + lane * 2) = __float22bfloat162_rn(a);
    } else {
        float a = FIRST ? bsum[lane] : 0.f;
        for (int r = r0; r <= r1; r++) {
            const __hip_bfloat16* Zr = Zb + (size_t)(r - r0) * NN * 64;
            int beg = row_ptr[r * NN + n];
            int end = row_ptr[r * NN + n + 1];
            for (int p = beg; p < end; p += 8) {
                int   ss[8]; float cc[8];
                #pragma unroll
                for (int j = 0; j < 8; j++) {
                    int q = (p + j < end) ? p + j : end - 1;
                    int2 e = edges[q];
                    ss[j] = e.x;
                    cc[j] = (p + j < end) ? __int_as_float(e.y) : 0.f;
                }
                float zz[8];
                #pragma unroll
                for (int j = 0; j < 8; j++)
                    zz[j] = __bfloat162float(Zr[(size_t)ss[j] * 64 + lane]);
                #pragma unroll
                for (int j = 0; j < 8; j++) a = fmaf(cc[j], zz[j], a);
            }
        }
        if constexpr (RELU) a = fmaxf(a, 0.f);
        if constexpr (OUT_F32) outf[(size_t)n * 64 + lane] = a;
        else outb[(size_t)n * 64 + lane] = __float2bfloat16(a);
    }
}

extern "C" void kernel_launch(void* const* d_in, const int* in_sizes, int n_in,
                              void* d_out, int out_size, void* d_ws, size_t ws_size,
                              hipStream_t stream) {
    const float* x   = (const float*)d_in[0];
    const int*   src = (const int*)  d_in[1];   // [4, 400000]
    const int*   dst = (const int*)  d_in[2];
    const float* W1  = (const float*)d_in[3];   // [4,128,128]
    const float* b1  = (const float*)d_in[4];   // [4,128]
    const float* W2  = (const float*)d_in[5];   // [4,128,64]
    const float* b2  = (const float*)d_in[6];   // [4,64]
    float* out = (float*)d_out;                 // [100000,64] fp32

    constexpr int RN = NR * NN;                 // 400000 rows total
    constexpr int NB = (RN + 1023) / 1024;

    char* p = (char*)d_ws;
    int*   deg_in_i  = (int*)p;   p += (size_t)RN * 4;
    float* rno       = (float*)p; p += (size_t)RN * 4;
    float* rni       = (float*)p; p += (size_t)RN * 4;
    int*   row_ptr   = (int*)p;   p += ((size_t)RN + 16) * 4;
    int*   cursor    = (int*)p;   p += (size_t)RN * 4;
    int*   blockSums = (int*)p;   p += 1024 * 4;
    int2*  edges     = (int2*)p;  p += (size_t)NR * NE * 8;   // 12.8 MB
    float* bsum1 = (float*)p; p += HF * 4;
    float* bsum2 = (float*)p; p += OUTF * 4;
    __hip_bfloat16* hb  = (__hip_bfloat16*)p; p += (size_t)NN * HF * 2;    // 25.6 MB
    __hip_bfloat16* Wt1 = (__hip_bfloat16*)p; p += (size_t)NR * HF * INF * 2;
    __hip_bfloat16* Wt2 = (__hip_bfloat16*)p; p += (size_t)NR * OUTF * HF * 2;
    __hip_bfloat16* Zb  = (__hip_bfloat16*)p; p += (size_t)2 * NN * HF * 2; // 51.2 MB
    int* parts = (int*)Zb;  // 2*NR*NWIN*SUB*WIN ints = 27.3 MB, dead before Zb written

    // ---- CSR build (no global atomics except cursor placement) ----
    conv_w_kernel<<<(NR * HF * INF + NR * OUTF * HF + 255) / 256, 256, 0, stream>>>(W1, W2, Wt1, Wt2);
    bsum_kernel<<<1, 192, 0, stream>>>(b1, b2, bsum1, bsum2);
    deg_win_kernel<<<dim3(NWIN * SUB, NR, 2), 256, 0, stream>>>(src, dst, parts);
    red_norm_kernel<<<(RN + 255) / 256, 256, 0, stream>>>(parts, deg_in_i, rno, rni);
    scan_block_kernel<<<NB, 256, 0, stream>>>(deg_in_i, row_ptr, blockSums, RN);
    scan_sums_kernel<<<1, 512, 0, stream>>>(blockSums, NB);
    scan_add_kernel<<<(RN + 255) / 256, 256, 0, stream>>>(row_ptr, blockSums, cursor, RN);
    csr_build_kernel<<<dim3((NE + 255) / 256, NR), 256, 0, stream>>>(
        src, dst, rno, rni, cursor, edges);

    constexpr int GB = (NN + 63) / 64;   // 1563
    constexpr int GG = (NN + 3) / 4;     // 25000

    // ---- layer 1: hb = relu( sum_r gather_r(x @ W1_r) + bsum1 ), 2 groups
    gemm_mfma<HF, float><<<dim3(GB, 2), 256, 0, stream>>>(x, Wt1, Zb);
    gather_fused<HF, true, false, false><<<GG, 256, 0, stream>>>(
        row_ptr, edges, Zb, nullptr, hb, bsum1, 0, 1);
    gemm_mfma<HF, float><<<dim3(GB, 2), 256, 0, stream>>>(x, Wt1 + (size_t)2 * HF * INF, Zb);
    gather_fused<HF, false, true, false><<<GG, 256, 0, stream>>>(
        row_ptr, edges, Zb, nullptr, hb, bsum1, 2, 3);

    // ---- layer 2: out = sum_r gather_r(hb @ W2_r) + bsum2 ----
    gemm_mfma<OUTF, __hip_bfloat16><<<dim3(GB, 4), 256, 0, stream>>>(hb, Wt2, Zb);
    gather_fused<OUTF, true, false, true><<<GG, 256, 0, stream>>>(
        row_ptr, edges, Zb, out, nullptr, bsum2, 0, 3);
}